// Round 7
// baseline (211.981 us; speedup 1.0000x reference)
//
#include <hip/hip_runtime.h>
#include <stdint.h>

// B=8, N=1024, D=1024.  out = relu(adj @ (y@W) / adj_sumrow + b + x)
// R7: corrected conflict-free BK=32 swizzle (phase = 8 lanes x 16B -> chunk
// must vary with l16>>1); f32->bf16 cvt fused into both GEMMs (one operand
// global_load_lds bf16, one manual f32 stage); 4-buffer depth-3 pipeline
// with hand-counted vmcnt; prep pass reduced to W-transpose only.

typedef float  f32x4  __attribute__((ext_vector_type(4)));
typedef __bf16 bf16x8 __attribute__((ext_vector_type(8)));

__device__ __forceinline__ unsigned int f2bf(float f) {
  union { float f; unsigned int u; } c; c.f = f;
  unsigned int u = c.u;
  u += 0x7FFFu + ((u >> 16) & 1u);   // RNE; inputs finite
  return u >> 16;
}

__device__ __forceinline__ void async_cp16(const void* g, void* l) {
  __builtin_amdgcn_global_load_lds(
      (const __attribute__((address_space(1))) unsigned int*)g,
      (__attribute__((address_space(3))) unsigned int*)l, 16, 0, 0);
}

__device__ __forceinline__ void lgkbar() {
  asm volatile("s_waitcnt lgkmcnt(0)\n\ts_barrier" ::: "memory");
}

__device__ __forceinline__ void zero_acc(f32x4 acc[4][4]) {
#pragma unroll
  for (int i = 0; i < 4; ++i)
#pragma unroll
    for (int j = 0; j < 4; ++j)
#pragma unroll
      for (int r = 0; r < 4; ++r) acc[i][j][r] = 0.0f;
}

// ---------------- prep: Wt[n][k] = W[k][n], f32 -> bf16 ----------------

__global__ __launch_bounds__(256) void k_prepW(
    const float* __restrict__ W, unsigned short* __restrict__ Wt)
{
  __shared__ float t[64][65];
  const int tx = threadIdx.x, ty = threadIdx.y;
  const int n0 = blockIdx.x * 64, k0 = blockIdx.y * 64;
#pragma unroll
  for (int r = ty; r < 64; r += 4)
    t[r][tx] = W[(size_t)(k0 + r) * 1024 + n0 + tx];
  __syncthreads();
#pragma unroll
  for (int r = ty; r < 64; r += 4)
    Wt[(size_t)(n0 + r) * 1024 + k0 + tx] = (unsigned short)f2bf(t[tx][r]);
}

// ---------------- core mainloop ----------------
// 128x128 tile, BK=32, 32 stages. Stage = 16 KB: [G bf16 128x32][F bf16 128x32].
// G staged via global_load_lds (granule = 16 rows x 64 B, 2/wave/stage).
// F staged manually: 4 float4/thread (128-B-line coalesced) -> cvt -> ds_write_b64.
// LDS swizzle: row r (64 B = 4 chunks of 16 B), phys chunk p = (q + ((r&15)>>1)) & 3.
//  - b128 frag-read phase (8 lanes): (row parity, p) covers all 8 combos -> 32 banks once.
//  - glds lane L: row L>>2, phys L&3 -> fetches logical q = ((L&3)-((L>>3)&7))&3.
//  - ds_write_b64 phase (16 lanes x 8 B): rows j*32+{0,1}, offsets tile banks 0..31 once.
// Pipeline: G depth-3 (buf (s+3)&3), F: regs loaded depth-2 (slots by parity),
// LDS-written 2 stages ahead. Two barriers/stage; steady-state wait = vmcnt(8).

__device__ __forceinline__ void gemm_core(
    const unsigned short* __restrict__ G, int sG, int g0,
    const float* __restrict__ F, int sF, int f0,
    int moff, int noff,              // ushort region offsets for m-/n-side frags
    f32x4 acc[4][4], unsigned short* lsm, int tid)
{
  const int lane = tid & 63, wave = tid >> 6;
  const int wm = (wave >> 1) * 64, wn = (wave & 1) * 64;
  const int quad = lane >> 4, l16 = lane & 15;
  const int fc = ((quad + (l16 >> 1)) & 3) * 8;            // frag phys chunk (ushorts)
  const int gr = lane >> 2;                                 // glds row in granule
  const int gq = (((lane & 3) - ((lane >> 3) & 7)) & 3) * 8;// glds global el offset
  const int fr = tid >> 3;                                  // F row (+j*32)
  const int fcol = (tid & 7) * 4;                           // F col (elements)
  const int wq = (tid & 7) >> 1;                            // F logical chunk
  const int whalf = (tid & 1) * 4;                          // F half-chunk (ushorts)

  auto issueG = [&](int s) {
    unsigned short* st = lsm + (s & 3) * 8192;
#pragma unroll
    for (int t = 0; t < 2; ++t) {
      const int g = wave * 2 + t;                           // wave-uniform granule
      async_cp16(G + (size_t)(g0 + g * 16 + gr) * sG + s * 32 + gq, st + g * 512);
    }
  };
  auto loadF = [&](int s, float4* slot) {
#pragma unroll
    for (int j = 0; j < 4; ++j)
      slot[j] = *(const float4*)(F + (size_t)(f0 + j * 32 + fr) * sF + s * 32 + fcol);
  };
  auto writeF = [&](int s, const float4* slot) {
    unsigned short* st = lsm + (s & 3) * 8192 + 4096;
#pragma unroll
    for (int j = 0; j < 4; ++j) {
      const int r = j * 32 + fr;
      const int p = (wq + ((r & 15) >> 1)) & 3;
      uint2 v;
      v.x = f2bf(slot[j].x) | (f2bf(slot[j].y) << 16);
      v.y = f2bf(slot[j].z) | (f2bf(slot[j].w) << 16);
      *(uint2*)(st + r * 32 + p * 8 + whalf) = v;
    }
  };
  auto compute = [&](int s) {
    const unsigned short* st = lsm + (s & 3) * 8192;
    bf16x8 mf[4], nf[4];
#pragma unroll
    for (int i = 0; i < 4; ++i)
      mf[i] = *(const bf16x8*)(st + moff + (wm + i * 16 + l16) * 32 + fc);
#pragma unroll
    for (int j = 0; j < 4; ++j)
      nf[j] = *(const bf16x8*)(st + noff + (wn + j * 16 + l16) * 32 + fc);
#pragma unroll
    for (int i = 0; i < 4; ++i)
#pragma unroll
      for (int j = 0; j < 4; ++j)
        acc[i][j] = __builtin_amdgcn_mfma_f32_16x16x32_bf16(mf[i], nf[j], acc[i][j], 0, 0, 0);
  };

  float4 s0[4], s1[4], t0[4], t1[4];
  // prologue issue order (instr counts): rB0(4) rB1(4) G0(2) G1(2) rB2(4) G2(2) rB3(4)
  loadF(0, t0);
  loadF(1, t1);
  issueG(0); issueG(1);
  loadF(2, s0);
  issueG(2);
  loadF(3, s1);
  asm volatile("s_waitcnt vmcnt(18)" ::: "memory");  // rB0 done
  writeF(0, t0);
  asm volatile("s_waitcnt vmcnt(14)" ::: "memory");  // rB1 done
  writeF(1, t1);
  lgkbar();

  auto body = [&](int s, float4* slot, int K1, bool doG, bool doW, bool doRB, bool fin) {
    if (doG) issueG(s + 3);
    if (doW) {
      if (K1 == 8)      asm volatile("s_waitcnt vmcnt(8)" ::: "memory");
      else if (K1 == 2) asm volatile("s_waitcnt vmcnt(2)" ::: "memory");
      writeF(s + 2, slot);
    }
    if (doRB) loadF(s + 4, slot);
    if (fin) asm volatile("s_waitcnt vmcnt(0)" ::: "memory");
    lgkbar();          // staging visible; G_s landed (vmcnt bookkeeping) + cross-wave
    compute(s);
    lgkbar();          // frag reads of buf s&3 done before future overwrite
  };

#pragma unroll 1
  for (int ss = 0; ss < 28; ss += 2) {
    body(ss,     s0, 8, true, true, true, false);
    body(ss + 1, s1, 8, true, true, true, false);
  }
  body(28, s0, 8, true,  true,  false, false);
  body(29, s1, 2, false, true,  false, false);
  body(30, s0, 0, false, false, false, false);
  body(31, s0, 0, false, false, false, true);
}

// ---------------- GEMM1: Sup2[d][8192] = Wt @ Y^T (bf16 out) ----------------

__global__ __launch_bounds__(256) void k_gemm1(
    const unsigned short* __restrict__ Wt,   // [1024][1024] bf16
    const float* __restrict__ Y,             // [8192][1024] f32
    unsigned short* __restrict__ Sup2)       // [1024][8192] bf16
{
  __shared__ __align__(16) unsigned short lsm[4 * 8192];   // 64 KB
  const int tid = threadIdx.x;
  const int n0 = blockIdx.x * 128, m0 = blockIdx.y * 128;

  f32x4 acc[4][4];
  zero_acc(acc);
  // G = Wt (m-side, region 0), F = Y (n-side, region 4096)
  gemm_core(Wt, 1024, m0, Y, 1024, n0, 0, 4096, acc, lsm, tid);

  const int lane = tid & 63, wave = tid >> 6;
  const int wm = (wave >> 1) * 64, wn = (wave & 1) * 64;
  const int quad = lane >> 4, l16 = lane & 15;
#pragma unroll
  for (int i = 0; i < 4; ++i) {
    const int mb = m0 + wm + i * 16 + quad * 4;
#pragma unroll
    for (int r = 0; r < 4; ++r) {
      unsigned short* row = Sup2 + ((size_t)(mb + r) << 13);
#pragma unroll
      for (int j = 0; j < 4; ++j)
        row[n0 + wn + j * 16 + l16] = (unsigned short)f2bf(acc[i][j][r]);
    }
  }
}

// ------- GEMM2: out = relu(adj @ Sup / rowsum + bias + x), f32 out -------

__global__ __launch_bounds__(256) void k_gemm2(
    const float* __restrict__ Adj,           // [8][1024][1024] f32
    const unsigned short* __restrict__ Sup2, // [1024][8192] bf16
    const float* __restrict__ x,
    const float* __restrict__ sumrow,        // [8][1024]
    const float* __restrict__ bias,          // [1024]
    float* __restrict__ out)
{
  __shared__ __align__(16) unsigned short lsm[4 * 8192];   // 64 KB
  const int tid = threadIdx.x;
  const int n0 = blockIdx.x * 128, m0 = blockIdx.y * 128, b = blockIdx.z;

  f32x4 acc[4][4];
  zero_acc(acc);
  // G = Sup2 slice (n-side, region 0), F = adj[b] (m-side, region 4096)
  gemm_core(Sup2 + ((size_t)b << 10), 8192, n0,
            Adj + ((size_t)b << 20), 1024, m0,
            4096, 0, acc, lsm, tid);

  const float* xb = x   + ((size_t)b << 20);
  float*       ob = out + ((size_t)b << 20);
  const float* sr = sumrow + ((size_t)b << 10);
  const int lane = tid & 63, wave = tid >> 6;
  const int wm = (wave >> 1) * 64, wn = (wave & 1) * 64;
  const int quad = lane >> 4, l16 = lane & 15;

  float bv[4];
#pragma unroll
  for (int j = 0; j < 4; ++j) bv[j] = bias[n0 + wn + j * 16 + l16];

#pragma unroll
  for (int i = 0; i < 4; ++i) {
    const int mb = m0 + wm + i * 16 + quad * 4;
#pragma unroll
    for (int r = 0; r < 4; ++r) {
      const int m = mb + r;
      const float inv = 1.0f / sr[m];
#pragma unroll
      for (int j = 0; j < 4; ++j) {
        const int n = n0 + wn + j * 16 + l16;
        const size_t idx = (((size_t)m) << 10) + n;
        float v = acc[i][j][r] * inv + bv[j] + xb[idx];
        ob[idx] = fmaxf(v, 0.0f);
      }
    }
  }
}

// ---------------- launcher ----------------

extern "C" void kernel_launch(void* const* d_in, const int* in_sizes, int n_in,
                              void* d_out, int out_size, void* d_ws, size_t ws_size,
                              hipStream_t stream) {
  const float* x      = (const float*)d_in[0];
  const float* y      = (const float*)d_in[1];
  const float* adj    = (const float*)d_in[2];
  const float* sumrow = (const float*)d_in[3];
  const float* W      = (const float*)d_in[4];
  const float* bias   = (const float*)d_in[5];
  float* out = (float*)d_out;

  char* ws = (char*)d_ws;
  unsigned short* wt   = (unsigned short*)(ws);                      //  2 MB
  unsigned short* sup2 = (unsigned short*)(ws + ((size_t)2 << 20));  // 16 MB

  k_prepW<<<dim3(16, 16), dim3(64, 4), 0, stream>>>(W, wt);
  k_gemm1<<<dim3(64, 8), dim3(256), 0, stream>>>(wt, y, sup2);
  k_gemm2<<<dim3(8, 8, 8), dim3(256), 0, stream>>>(adj, sup2, x, sumrow, bias, out);
}